// Round 1
// baseline (3170.379 us; speedup 1.0000x reference)
//
#include <hip/hip_runtime.h>

// Problem constants (match reference setup_inputs)
#define D 64
constexpr int Pn  = 100000;
constexpr int Un  = 20000;
constexpr int Rn  = 1000;
constexpr int Cn  = 500;
constexpr int Tn  = 50;
constexpr int Bn  = 4096;
constexpr int ETn = 50000;
constexpr int NNZ_COL = 1000000;
constexpr int NNZ_REG = 300000;
constexpr int NNZ_CAT = 300000;
constexpr int NNZ_T   = 1000000;

static inline int cdiv(int a, int b) { return (a + b - 1) / b; }

// ---------------------------------------------------------------------------
// gate: out = x * sigmoid(x @ W + b), written to two destinations (p and acc)
// wave-per-row; W column `lane` held in 64 VGPRs; row broadcast via LDS.
// ---------------------------------------------------------------------------
__global__ __launch_bounds__(256) void gate_kernel(
    const float* __restrict__ Xin, const float* __restrict__ W,
    const float* __restrict__ bias, float* __restrict__ Pout,
    float* __restrict__ Aout, int N) {
  __shared__ float sx[4][D];
  int tid = threadIdx.x, wv = tid >> 6, lane = tid & 63;
  float wcol[D];
#pragma unroll
  for (int k = 0; k < D; ++k) wcol[k] = W[k * D + lane];
  float bl = bias[lane];
  for (int row = blockIdx.x * 4 + wv; row < N; row += gridDim.x * 4) {
    float x = Xin[row * D + lane];
    sx[wv][lane] = x;
    float y = 0.f;
#pragma unroll
    for (int k = 0; k < D; ++k) y += sx[wv][k] * wcol[k];
    float s = 1.f / (1.f + __expf(-(y + bl)));
    float o = x * s;
    Pout[row * D + lane] = o;
    Aout[row * D + lane] = o;
  }
}

// Y = X @ W  (N x 64) @ (64 x 64)
__global__ __launch_bounds__(256) void matmul_kernel(
    const float* __restrict__ Xin, const float* __restrict__ W,
    float* __restrict__ Y, int N) {
  __shared__ float sx[4][D];
  int tid = threadIdx.x, wv = tid >> 6, lane = tid & 63;
  float wcol[D];
#pragma unroll
  for (int k = 0; k < D; ++k) wcol[k] = W[k * D + lane];
  for (int row = blockIdx.x * 4 + wv; row < N; row += gridDim.x * 4) {
    sx[wv][lane] = Xin[row * D + lane];
    float y = 0.f;
#pragma unroll
    for (int k = 0; k < D; ++k) y += sx[wv][k] * wcol[k];
    Y[row * D + lane] = y;
  }
}

// Y = A @ W1 + B @ W2  (fused hetero edge update)
__global__ __launch_bounds__(256) void fused2_kernel(
    const float* __restrict__ A, const float* __restrict__ Bm,
    const float* __restrict__ W1, const float* __restrict__ W2,
    float* __restrict__ Y, int N) {
  __shared__ float sa[4][D], sb2[4][D];
  int tid = threadIdx.x, wv = tid >> 6, lane = tid & 63;
  float w1[D], w2[D];
#pragma unroll
  for (int k = 0; k < D; ++k) {
    w1[k] = W1[k * D + lane];
    w2[k] = W2[k * D + lane];
  }
  for (int row = blockIdx.x * 4 + wv; row < N; row += gridDim.x * 4) {
    sa[wv][lane]  = A[row * D + lane];
    sb2[wv][lane] = Bm[row * D + lane];
    float y = 0.f;
#pragma unroll
    for (int k = 0; k < D; ++k) y += sa[wv][k] * w1[k] + sb2[wv][k] * w2[k];
    Y[row * D + lane] = y;
  }
}

// Y[rows[n], :] += vals[n] * X[cols[n], :]   via f32 atomics.
// One wave handles 64 nnz: coalesced index loads, broadcast via shfl.
__global__ __launch_bounds__(256) void spmm_kernel(
    const int* __restrict__ rows, const int* __restrict__ cols,
    const float* __restrict__ vals, const float* __restrict__ X,
    float* __restrict__ Y, int nnz) {
  int lane = threadIdx.x & 63;
  int wid = (int)((blockIdx.x * blockDim.x + threadIdx.x) >> 6);
  int base = wid * 64;
  if (base >= nnz) return;
  int n = base + lane;
  int r = 0, c = 0;
  float v = 0.f;
  if (n < nnz) { r = rows[n]; c = cols[n]; v = vals[n]; }
  int cnt = min(64, nnz - base);
  for (int j = 0; j < cnt; ++j) {
    int rj = __shfl(r, j);
    int cj = __shfl(c, j);
    float vj = __shfl(v, j);
    atomicAdd(&Y[rj * D + lane], vj * X[cj * D + lane]);
  }
}

// p += t; acc += p
__global__ __launch_bounds__(256) void resid2_kernel(
    float* __restrict__ p, const float* __restrict__ t,
    float* __restrict__ acc, int n) {
  int i = blockIdx.x * blockDim.x + threadIdx.x;
  if (i < n) {
    float v = p[i] + t[i];
    p[i] = v;
    acc[i] += v;
  }
}

// a = src; b = src
__global__ __launch_bounds__(256) void copy2_kernel(
    const float* __restrict__ s, float* __restrict__ a, float* __restrict__ b,
    int n) {
  int i = blockIdx.x * blockDim.x + threadIdx.x;
  if (i < n) {
    float v = s[i];
    a[i] = v;
    b[i] = v;
  }
}

// Final pooling: masked mean over T of 4 padded tables + user add, scale 1/3.
__global__ __launch_bounds__(256) void final_kernel(
    const int* __restrict__ user_idx, const int* __restrict__ seq,
    const int* __restrict__ mask, const float* __restrict__ colP,
    const float* __restrict__ transP, const float* __restrict__ regP,
    const float* __restrict__ catP, const float* __restrict__ colU,
    float* __restrict__ out) {
  int wid = (int)((blockIdx.x * blockDim.x + threadIdx.x) >> 6);
  int lane = threadIdx.x & 63;
  if (wid >= Bn) return;
  float sc = 0.f, st = 0.f, sr = 0.f, sca = 0.f;
  int cnt = 0;
  for (int t = 0; t < Tn; ++t) {
    int m = mask[wid * Tn + t];
    int idx = seq[wid * Tn + t];
    cnt += m;
    if (m && idx < Pn) {
      sc  += colP[idx * D + lane];
      st  += transP[idx * D + lane];
      sr  += regP[idx * D + lane];
      sca += catP[idx * D + lane];
    }
  }
  float dn = 1.f / (float)(cnt > 0 ? cnt : 1);
  const float inv = 1.f / 3.f;  // 1/(N_LAYERS+1), common to all four nets
  int u = user_idx[wid];
  out[0 * Bn * D + wid * D + lane] = (colU[u * D + lane] + sc * dn) * inv;
  out[1 * Bn * D + wid * D + lane] = st * dn * inv;
  out[2 * Bn * D + wid * D + lane] = sr * dn * inv;
  out[3 * Bn * D + wid * D + lane] = sca * dn * inv;
}

extern "C" void kernel_launch(void* const* d_in, const int* in_sizes, int n_in,
                              void* d_out, int out_size, void* d_ws,
                              size_t ws_size, hipStream_t stream) {
  (void)in_sizes; (void)n_in; (void)out_size; (void)ws_size;
  const int*   user_idx      = (const int*)d_in[0];
  const int*   user_seq      = (const int*)d_in[1];
  const int*   user_seq_mask = (const int*)d_in[2];
  const int*   col_poi_idx   = (const int*)d_in[3];
  const int*   col_user_idx  = (const int*)d_in[4];
  const float* col_vals_pe   = (const float*)d_in[5];
  const float* col_vals_ep   = (const float*)d_in[6];
  const int*   reg_poi_idx   = (const int*)d_in[7];
  const int*   reg_region_idx= (const int*)d_in[8];
  const float* reg_vals_pe   = (const float*)d_in[9];
  const float* reg_vals_ep   = (const float*)d_in[10];
  const int*   cat_poi_idx   = (const int*)d_in[11];
  const int*   cat_cat_idx   = (const int*)d_in[12];
  const float* cat_vals_pe   = (const float*)d_in[13];
  const float* cat_vals_ep   = (const float*)d_in[14];
  const int*   trans_poi_idx = (const int*)d_in[15];
  const int*   trans_edge_idx= (const int*)d_in[16];
  const float* trans_vals_tar= (const float*)d_in[17];
  const float* trans_vals_src= (const float*)d_in[18];
  const float* poi_emb       = (const float*)d_in[19];
  const float* user_emb      = (const float*)d_in[20];
  const float* region_emb    = (const float*)d_in[21];
  const float* cat_emb       = (const float*)d_in[22];
  const float* w_gate_col    = (const float*)d_in[23];
  const float* b_gate_col    = (const float*)d_in[24];
  const float* w_gate_trans  = (const float*)d_in[25];
  const float* b_gate_trans  = (const float*)d_in[26];
  const float* w_gate_reg    = (const float*)d_in[27];
  const float* b_gate_reg    = (const float*)d_in[28];
  const float* w_gate_cat    = (const float*)d_in[29];
  const float* b_gate_cat    = (const float*)d_in[30];
  const float* col_Wp = (const float*)d_in[31];
  const float* col_We = (const float*)d_in[32];
  const float* col_Wf = (const float*)d_in[33];
  const float* reg_Wp = (const float*)d_in[34];
  const float* reg_We = (const float*)d_in[35];
  const float* reg_Wf = (const float*)d_in[36];
  const float* cat_Wp = (const float*)d_in[37];
  const float* cat_We = (const float*)d_in[38];
  const float* cat_Wf = (const float*)d_in[39];

  float* ws = (float*)d_ws;
  size_t off = 0;
  auto alloc = [&](size_t n) { float* p = ws + off; off += n; return p; };
  const size_t PD = (size_t)Pn * D;
  const size_t ED = (size_t)ETn * D;  // max edge-side rows (ET=50000 > U)

  float* colP   = alloc(PD);           // persistent acc_p (col)
  float* regP   = alloc(PD);
  float* catP   = alloc(PD);
  float* transP = alloc(PD);
  float* colU   = alloc((size_t)Un * D);  // persistent acc_e (col)
  float* p_buf  = alloc(PD);
  float* tmpP   = alloc(PD);
  float* e_buf  = alloc(ED);
  float* tmpE1  = alloc(ED);
  float* tmpE2  = alloc(ED);
  float* acce   = alloc(ED);           // scratch acc_e for reg/cat
  float* WeWf   = alloc(D * D);

  auto spmm = [&](const int* r, const int* c, const float* v, const float* X,
                  float* Y, int nnz) {
    int waves = cdiv(nnz, 64);
    spmm_kernel<<<cdiv(waves, 4), 256, 0, stream>>>(r, c, v, X, Y, nnz);
  };

  auto hetero = [&](const float* wg, const float* bg, const float* edge_emb,
                    int Ne, const int* poi_idx, const int* edge_idx,
                    const float* v_pe, const float* v_ep, const float* Wp,
                    const float* We, const float* Wf, int nnz, float* accP,
                    float* accE) {
    gate_kernel<<<cdiv(Pn, 4), 256, 0, stream>>>(poi_emb, wg, bg, p_buf, accP, Pn);
    copy2_kernel<<<cdiv(Ne * D, 256), 256, 0, stream>>>(edge_emb, e_buf, accE, Ne * D);
    matmul_kernel<<<16, 256, 0, stream>>>(We, Wf + D * D, WeWf, D);  // We @ Wf_bot
    for (int l = 0; l < 2; ++l) {
      matmul_kernel<<<cdiv(Pn, 4), 256, 0, stream>>>(p_buf, Wp, tmpP, Pn);
      hipMemsetAsync(tmpE1, 0, (size_t)Ne * D * sizeof(float), stream);
      spmm(edge_idx, poi_idx, v_pe, tmpP, tmpE1, nnz);          // poi_msg
      fused2_kernel<<<cdiv(Ne, 4), 256, 0, stream>>>(tmpE1, e_buf, Wf, WeWf, tmpE2, Ne);
      hipMemsetAsync(tmpP, 0, PD * sizeof(float), stream);
      spmm(poi_idx, edge_idx, v_ep, tmpE2, tmpP, nnz);          // prop
      resid2_kernel<<<cdiv((int)PD, 256), 256, 0, stream>>>(p_buf, tmpP, accP, (int)PD);
      resid2_kernel<<<cdiv(Ne * D, 256), 256, 0, stream>>>(e_buf, tmpE2, accE, Ne * D);
    }
  };

  // --- three hetero nets (acc scaled by 1/3 in final kernel) ---
  hetero(w_gate_col, b_gate_col, user_emb, Un, col_poi_idx, col_user_idx,
         col_vals_pe, col_vals_ep, col_Wp, col_We, col_Wf, NNZ_COL, colP, colU);
  hetero(w_gate_reg, b_gate_reg, region_emb, Rn, reg_poi_idx, reg_region_idx,
         reg_vals_pe, reg_vals_ep, reg_Wp, reg_We, reg_Wf, NNZ_REG, regP, acce);
  hetero(w_gate_cat, b_gate_cat, cat_emb, Cn, cat_poi_idx, cat_cat_idx,
         cat_vals_pe, cat_vals_ep, cat_Wp, cat_We, cat_Wf, NNZ_CAT, catP, acce);

  // --- directed trans net ---
  gate_kernel<<<cdiv(Pn, 4), 256, 0, stream>>>(poi_emb, w_gate_trans,
                                               b_gate_trans, p_buf, transP, Pn);
  for (int l = 0; l < 2; ++l) {
    hipMemsetAsync(tmpE1, 0, (size_t)ETn * D * sizeof(float), stream);
    spmm(trans_edge_idx, trans_poi_idx, trans_vals_tar, p_buf, tmpE1, NNZ_T);
    hipMemsetAsync(tmpP, 0, PD * sizeof(float), stream);
    spmm(trans_poi_idx, trans_edge_idx, trans_vals_src, tmpE1, tmpP, NNZ_T);
    resid2_kernel<<<cdiv((int)PD, 256), 256, 0, stream>>>(p_buf, tmpP, transP, (int)PD);
  }

  // --- sequence pooling + output ---
  final_kernel<<<cdiv(Bn * 64, 256), 256, 0, stream>>>(
      user_idx, user_seq, user_seq_mask, colP, transP, regP, catP, colU,
      (float*)d_out);
}

// Round 2
// 2504.879 us; speedup vs baseline: 1.2657x; 1.2657x over previous
//
#include <hip/hip_runtime.h>

// Problem constants (match reference setup_inputs)
#define D 64
constexpr int Pn  = 100000;
constexpr int Un  = 20000;
constexpr int Rn  = 1000;
constexpr int Cn  = 500;
constexpr int Tn  = 50;
constexpr int Bn  = 4096;
constexpr int ETn = 50000;
constexpr int NNZ_COL = 1000000;
constexpr int NNZ_REG = 300000;
constexpr int NNZ_CAT = 300000;
constexpr int NNZ_T   = 1000000;

static inline int cdiv(int a, int b) { return (a + b - 1) / b; }

// ---------------------------------------------------------------------------
// gate: out = x * sigmoid(x @ W + b), written to two destinations
// ---------------------------------------------------------------------------
__global__ __launch_bounds__(256) void gate_kernel(
    const float* __restrict__ Xin, const float* __restrict__ W,
    const float* __restrict__ bias, float* __restrict__ Pout,
    float* __restrict__ Aout, int N) {
  __shared__ float sx[4][D];
  int tid = threadIdx.x, wv = tid >> 6, lane = tid & 63;
  float wcol[D];
#pragma unroll
  for (int k = 0; k < D; ++k) wcol[k] = W[k * D + lane];
  float bl = bias[lane];
  for (int row = blockIdx.x * 4 + wv; row < N; row += gridDim.x * 4) {
    float x = Xin[row * D + lane];
    sx[wv][lane] = x;
    float y = 0.f;
#pragma unroll
    for (int k = 0; k < D; ++k) y += sx[wv][k] * wcol[k];
    float s = 1.f / (1.f + __expf(-(y + bl)));
    float o = x * s;
    Pout[row * D + lane] = o;
    Aout[row * D + lane] = o;
  }
}

// Y = X @ W  (N x 64) @ (64 x 64)
__global__ __launch_bounds__(256) void matmul_kernel(
    const float* __restrict__ Xin, const float* __restrict__ W,
    float* __restrict__ Y, int N) {
  __shared__ float sx[4][D];
  int tid = threadIdx.x, wv = tid >> 6, lane = tid & 63;
  float wcol[D];
#pragma unroll
  for (int k = 0; k < D; ++k) wcol[k] = W[k * D + lane];
  for (int row = blockIdx.x * 4 + wv; row < N; row += gridDim.x * 4) {
    sx[wv][lane] = Xin[row * D + lane];
    float y = 0.f;
#pragma unroll
    for (int k = 0; k < D; ++k) y += sx[wv][k] * wcol[k];
    Y[row * D + lane] = y;
  }
}

// Y = A @ W1 + B @ W2  (fused hetero edge update)
__global__ __launch_bounds__(256) void fused2_kernel(
    const float* __restrict__ A, const float* __restrict__ Bm,
    const float* __restrict__ W1, const float* __restrict__ W2,
    float* __restrict__ Y, int N) {
  __shared__ float sa[4][D], sb2[4][D];
  int tid = threadIdx.x, wv = tid >> 6, lane = tid & 63;
  float w1[D], w2[D];
#pragma unroll
  for (int k = 0; k < D; ++k) {
    w1[k] = W1[k * D + lane];
    w2[k] = W2[k * D + lane];
  }
  for (int row = blockIdx.x * 4 + wv; row < N; row += gridDim.x * 4) {
    sa[wv][lane]  = A[row * D + lane];
    sb2[wv][lane] = Bm[row * D + lane];
    float y = 0.f;
#pragma unroll
    for (int k = 0; k < D; ++k) y += sa[wv][k] * w1[k] + sb2[wv][k] * w2[k];
    Y[row * D + lane] = y;
  }
}

// ---------------------------------------------------------------------------
// Counting sort: hist -> exclusive scan -> scatter (stable-ish; order within a
// row is atomic-race-determined, fine for float-sum tolerance)
// ---------------------------------------------------------------------------
__global__ __launch_bounds__(256) void hist_kernel(
    const int* __restrict__ keys, int* __restrict__ counts, int nnz) {
  int i = blockIdx.x * blockDim.x + threadIdx.x;
  if (i < nnz) atomicAdd(&counts[keys[i]], 1);
}

// per-block exclusive scan over 4096 elems; block totals out
__global__ __launch_bounds__(1024) void scan_blocks_kernel(
    const int* __restrict__ in, int* __restrict__ out, int* __restrict__ btot,
    int n) {
  __shared__ int lds[16];
  int tid = threadIdx.x, lane = tid & 63, wv = tid >> 6;
  int base = blockIdx.x * 4096;
  int x[4];
  int s = 0;
#pragma unroll
  for (int e = 0; e < 4; ++e) {
    int i = base + tid * 4 + e;
    x[e] = (i < n) ? in[i] : 0;
    s += x[e];
  }
  int sc = s;
#pragma unroll
  for (int d = 1; d < 64; d <<= 1) {
    int y = __shfl_up(sc, d);
    if (lane >= d) sc += y;
  }
  if (lane == 63) lds[wv] = sc;
  __syncthreads();
  if (tid < 16) {
    int w = lds[tid];
#pragma unroll
    for (int d = 1; d < 16; d <<= 1) {
      int y = __shfl_up(w, d);
      if (lane >= d) w += y;
    }
    lds[tid] = w;
  }
  __syncthreads();
  int woff = (wv == 0) ? 0 : lds[wv - 1];
  int excl = woff + sc - s;
#pragma unroll
  for (int e = 0; e < 4; ++e) {
    int i = base + tid * 4 + e;
    if (i < n) out[i] = excl;
    excl += x[e];
  }
  if (tid == 0) btot[blockIdx.x] = lds[15];
}

__global__ __launch_bounds__(64) void scan_totals_kernel(int* btot, int nb) {
  int lane = threadIdx.x;
  int x = (lane < nb) ? btot[lane] : 0;
  int sc = x;
#pragma unroll
  for (int d = 1; d < 64; d <<= 1) {
    int y = __shfl_up(sc, d);
    if (lane >= d) sc += y;
  }
  if (lane < nb) btot[lane] = sc - x;  // exclusive
}

__global__ __launch_bounds__(256) void add_off_kernel(
    int* __restrict__ out, const int* __restrict__ btot, int n) {
  int i = blockIdx.x * blockDim.x + threadIdx.x;
  if (i < n) out[i] += btot[i >> 12];
}

__global__ __launch_bounds__(256) void scatter_kernel(
    const int* __restrict__ keys, const int* __restrict__ other,
    const float* __restrict__ vals, int* __restrict__ cursor,
    int* __restrict__ sr, int* __restrict__ sc, float* __restrict__ sv,
    int nnz) {
  int i = blockIdx.x * blockDim.x + threadIdx.x;
  if (i >= nnz) return;
  int k = keys[i];
  int pos = atomicAdd(&cursor[k], 1);
  sr[pos] = k;
  sc[pos] = other[i];
  sv[pos] = vals[i];
}

// ---------------------------------------------------------------------------
// Segmented SpMM over row-sorted triples: one wave = 64 nnz window;
// accumulate runs of equal row in a register, one atomicAdd per run.
// ---------------------------------------------------------------------------
__global__ __launch_bounds__(256) void spmm_sorted_kernel(
    const int* __restrict__ sr, const int* __restrict__ sc,
    const float* __restrict__ sv, const float* __restrict__ X,
    float* __restrict__ Y, int nnz) {
  int lane = threadIdx.x & 63;
  int wid = (int)((blockIdx.x * (long)blockDim.x + threadIdx.x) >> 6);
  int base = wid * 64;
  if (base >= nnz) return;
  int n = base + lane;
  int r = 0, c = 0;
  float v = 0.f;
  if (n < nnz) { r = sr[n]; c = sc[n]; v = sv[n]; }
  int cnt = min(64, nnz - base);
  int cur = __shfl(r, 0);
  float acc = 0.f;
  for (int j = 0; j < cnt; ++j) {
    int rj = __shfl(r, j);
    int cj = __shfl(c, j);
    float vj = __shfl(v, j);
    if (rj != cur) {  // wave-uniform branch
      atomicAdd(&Y[(size_t)cur * D + lane], acc);
      acc = 0.f;
      cur = rj;
    }
    acc += vj * X[(size_t)cj * D + lane];
  }
  atomicAdd(&Y[(size_t)cur * D + lane], acc);
}

// p += t; acc += p   (float4)
__global__ __launch_bounds__(256) void resid2_kernel(
    float4* __restrict__ p, const float4* __restrict__ t,
    float4* __restrict__ acc, int n4) {
  int i = blockIdx.x * blockDim.x + threadIdx.x;
  if (i < n4) {
    float4 a = p[i], b = t[i], c = acc[i];
    a.x += b.x; a.y += b.y; a.z += b.z; a.w += b.w;
    p[i] = a;
    c.x += a.x; c.y += a.y; c.z += a.z; c.w += a.w;
    acc[i] = c;
  }
}

// a = src; b = src  (float4)
__global__ __launch_bounds__(256) void copy2_kernel(
    const float4* __restrict__ s, float4* __restrict__ a,
    float4* __restrict__ b, int n4) {
  int i = blockIdx.x * blockDim.x + threadIdx.x;
  if (i < n4) {
    float4 v = s[i];
    a[i] = v;
    b[i] = v;
  }
}

// Final pooling: masked mean over T of 4 padded tables + user add, scale 1/3.
__global__ __launch_bounds__(256) void final_kernel(
    const int* __restrict__ user_idx, const int* __restrict__ seq,
    const int* __restrict__ mask, const float* __restrict__ colP,
    const float* __restrict__ transP, const float* __restrict__ regP,
    const float* __restrict__ catP, const float* __restrict__ colU,
    float* __restrict__ out) {
  int wid = (int)((blockIdx.x * blockDim.x + threadIdx.x) >> 6);
  int lane = threadIdx.x & 63;
  if (wid >= Bn) return;
  float sc = 0.f, st = 0.f, sr = 0.f, sca = 0.f;
  int cnt = 0;
  for (int t = 0; t < Tn; ++t) {
    int m = mask[wid * Tn + t];
    int idx = seq[wid * Tn + t];
    cnt += m;
    if (m && idx < Pn) {
      sc  += colP[idx * D + lane];
      st  += transP[idx * D + lane];
      sr  += regP[idx * D + lane];
      sca += catP[idx * D + lane];
    }
  }
  float dn = 1.f / (float)(cnt > 0 ? cnt : 1);
  const float inv = 1.f / 3.f;  // 1/(N_LAYERS+1), common to all four nets
  int u = user_idx[wid];
  out[0 * Bn * D + wid * D + lane] = (colU[u * D + lane] + sc * dn) * inv;
  out[1 * Bn * D + wid * D + lane] = st * dn * inv;
  out[2 * Bn * D + wid * D + lane] = sr * dn * inv;
  out[3 * Bn * D + wid * D + lane] = sca * dn * inv;
}

extern "C" void kernel_launch(void* const* d_in, const int* in_sizes, int n_in,
                              void* d_out, int out_size, void* d_ws,
                              size_t ws_size, hipStream_t stream) {
  (void)in_sizes; (void)n_in; (void)out_size; (void)ws_size;
  const int*   user_idx      = (const int*)d_in[0];
  const int*   user_seq      = (const int*)d_in[1];
  const int*   user_seq_mask = (const int*)d_in[2];
  const int*   col_poi_idx   = (const int*)d_in[3];
  const int*   col_user_idx  = (const int*)d_in[4];
  const float* col_vals_pe   = (const float*)d_in[5];
  const float* col_vals_ep   = (const float*)d_in[6];
  const int*   reg_poi_idx   = (const int*)d_in[7];
  const int*   reg_region_idx= (const int*)d_in[8];
  const float* reg_vals_pe   = (const float*)d_in[9];
  const float* reg_vals_ep   = (const float*)d_in[10];
  const int*   cat_poi_idx   = (const int*)d_in[11];
  const int*   cat_cat_idx   = (const int*)d_in[12];
  const float* cat_vals_pe   = (const float*)d_in[13];
  const float* cat_vals_ep   = (const float*)d_in[14];
  const int*   trans_poi_idx = (const int*)d_in[15];
  const int*   trans_edge_idx= (const int*)d_in[16];
  const float* trans_vals_tar= (const float*)d_in[17];
  const float* trans_vals_src= (const float*)d_in[18];
  const float* poi_emb       = (const float*)d_in[19];
  const float* user_emb      = (const float*)d_in[20];
  const float* region_emb    = (const float*)d_in[21];
  const float* cat_emb       = (const float*)d_in[22];
  const float* w_gate_col    = (const float*)d_in[23];
  const float* b_gate_col    = (const float*)d_in[24];
  const float* w_gate_trans  = (const float*)d_in[25];
  const float* b_gate_trans  = (const float*)d_in[26];
  const float* w_gate_reg    = (const float*)d_in[27];
  const float* b_gate_reg    = (const float*)d_in[28];
  const float* w_gate_cat    = (const float*)d_in[29];
  const float* b_gate_cat    = (const float*)d_in[30];
  const float* col_Wp = (const float*)d_in[31];
  const float* col_We = (const float*)d_in[32];
  const float* col_Wf = (const float*)d_in[33];
  const float* reg_Wp = (const float*)d_in[34];
  const float* reg_We = (const float*)d_in[35];
  const float* reg_Wf = (const float*)d_in[36];
  const float* cat_Wp = (const float*)d_in[37];
  const float* cat_We = (const float*)d_in[38];
  const float* cat_Wf = (const float*)d_in[39];

  float* ws = (float*)d_ws;
  size_t off = 0;
  auto alloc = [&](size_t n) { float* p = ws + off; off += n; return p; };
  const size_t PD = (size_t)Pn * D;   // 6.4M floats
  const size_t UD = (size_t)Un * D;   // 1.28M
  const size_t ED = (size_t)ETn * D;  // 3.2M

  float* colP   = alloc(PD);
  float* regP   = alloc(PD);
  float* catP   = alloc(PD);
  float* transP = alloc(PD);
  float* colU   = alloc(UD);
  float* p_buf  = alloc(PD);
  float* tmpP   = alloc(PD);
  float* e_buf  = alloc(UD);          // hetero edge features (max Un rows)
  float* tmpE2  = alloc(UD);
  float* tmpE1  = alloc(ED);          // pe-spmm dest (max ETn rows)
  float* acce   = alloc((size_t)Rn * D);  // scratch acc_e for reg/cat
  float* WeWf   = alloc(D * D);
  // sorted triples: pe-direction (s1) and ep-direction (s2)
  int*   s1r = (int*)alloc(NNZ_T);
  int*   s1c = (int*)alloc(NNZ_T);
  float* s1v = alloc(NNZ_T);
  int*   s2r = (int*)alloc(NNZ_T);
  int*   s2c = (int*)alloc(NNZ_T);
  float* s2v = alloc(NNZ_T);
  int*   counts = (int*)alloc(Pn + 2);
  int*   cursor = (int*)alloc(Pn + 2);
  int*   btot   = (int*)alloc(64);

  auto sort_pairs = [&](const int* keys, const int* other, const float* vals,
                        int nnz, int nkeys, int* sr, int* scc, float* sv) {
    hipMemsetAsync(counts, 0, (size_t)nkeys * sizeof(int), stream);
    hist_kernel<<<cdiv(nnz, 256), 256, 0, stream>>>(keys, counts, nnz);
    int nb = cdiv(nkeys, 4096);
    scan_blocks_kernel<<<nb, 1024, 0, stream>>>(counts, cursor, btot, nkeys);
    scan_totals_kernel<<<1, 64, 0, stream>>>(btot, nb);
    add_off_kernel<<<cdiv(nkeys, 256), 256, 0, stream>>>(cursor, btot, nkeys);
    scatter_kernel<<<cdiv(nnz, 256), 256, 0, stream>>>(keys, other, vals,
                                                       cursor, sr, scc, sv, nnz);
  };

  auto spmm = [&](const int* sr, const int* scc, const float* sv,
                  const float* X, float* Y, int nnz) {
    int waves = cdiv(nnz, 64);
    spmm_sorted_kernel<<<cdiv(waves, 4), 256, 0, stream>>>(sr, scc, sv, X, Y, nnz);
  };

  auto hetero = [&](const float* wg, const float* bg, const float* edge_emb,
                    int Ne, const int* poi_idx, const int* edge_idx,
                    const float* v_pe, const float* v_ep, const float* Wp,
                    const float* We, const float* Wf, int nnz, float* accP,
                    float* accE) {
    // sorts reused across both layers
    sort_pairs(edge_idx, poi_idx, v_pe, nnz, Ne, s1r, s1c, s1v);  // dest=edge
    sort_pairs(poi_idx, edge_idx, v_ep, nnz, Pn, s2r, s2c, s2v);  // dest=poi
    gate_kernel<<<cdiv(Pn, 4), 256, 0, stream>>>(poi_emb, wg, bg, p_buf, accP, Pn);
    copy2_kernel<<<cdiv(Ne * D / 4, 256), 256, 0, stream>>>(
        (const float4*)edge_emb, (float4*)e_buf, (float4*)accE, Ne * D / 4);
    matmul_kernel<<<16, 256, 0, stream>>>(We, Wf + D * D, WeWf, D);  // We@Wf_bot
    for (int l = 0; l < 2; ++l) {
      matmul_kernel<<<cdiv(Pn, 4), 256, 0, stream>>>(p_buf, Wp, tmpP, Pn);
      hipMemsetAsync(tmpE1, 0, (size_t)Ne * D * sizeof(float), stream);
      spmm(s1r, s1c, s1v, tmpP, tmpE1, nnz);  // poi_msg (dest=edge rows)
      fused2_kernel<<<cdiv(Ne, 4), 256, 0, stream>>>(tmpE1, e_buf, Wf, WeWf,
                                                     tmpE2, Ne);
      hipMemsetAsync(tmpP, 0, PD * sizeof(float), stream);
      spmm(s2r, s2c, s2v, tmpE2, tmpP, nnz);  // prop (dest=poi rows)
      resid2_kernel<<<cdiv((int)(PD / 4), 256), 256, 0, stream>>>(
          (float4*)p_buf, (const float4*)tmpP, (float4*)accP, (int)(PD / 4));
      resid2_kernel<<<cdiv(Ne * D / 4, 256), 256, 0, stream>>>(
          (float4*)e_buf, (const float4*)tmpE2, (float4*)accE, Ne * D / 4);
    }
  };

  // --- three hetero nets (acc scaled by 1/3 in final kernel) ---
  hetero(w_gate_col, b_gate_col, user_emb, Un, col_poi_idx, col_user_idx,
         col_vals_pe, col_vals_ep, col_Wp, col_We, col_Wf, NNZ_COL, colP, colU);
  hetero(w_gate_reg, b_gate_reg, region_emb, Rn, reg_poi_idx, reg_region_idx,
         reg_vals_pe, reg_vals_ep, reg_Wp, reg_We, reg_Wf, NNZ_REG, regP, acce);
  hetero(w_gate_cat, b_gate_cat, cat_emb, Cn, cat_poi_idx, cat_cat_idx,
         cat_vals_pe, cat_vals_ep, cat_Wp, cat_We, cat_Wf, NNZ_CAT, catP, acce);

  // --- directed trans net ---
  sort_pairs(trans_edge_idx, trans_poi_idx, trans_vals_tar, NNZ_T, ETn,
             s1r, s1c, s1v);                                   // dest=edge
  sort_pairs(trans_poi_idx, trans_edge_idx, trans_vals_src, NNZ_T, Pn,
             s2r, s2c, s2v);                                   // dest=poi
  gate_kernel<<<cdiv(Pn, 4), 256, 0, stream>>>(poi_emb, w_gate_trans,
                                               b_gate_trans, p_buf, transP, Pn);
  for (int l = 0; l < 2; ++l) {
    hipMemsetAsync(tmpE1, 0, ED * sizeof(float), stream);
    spmm(s1r, s1c, s1v, p_buf, tmpE1, NNZ_T);   // msg_tar
    hipMemsetAsync(tmpP, 0, PD * sizeof(float), stream);
    spmm(s2r, s2c, s2v, tmpE1, tmpP, NNZ_T);    // msg_src
    resid2_kernel<<<cdiv((int)(PD / 4), 256), 256, 0, stream>>>(
        (float4*)p_buf, (const float4*)tmpP, (float4*)transP, (int)(PD / 4));
  }

  // --- sequence pooling + output ---
  final_kernel<<<cdiv(Bn * 64, 256), 256, 0, stream>>>(
      user_idx, user_seq, user_seq_mask, colP, transP, regP, catP, colU,
      (float*)d_out);
}

// Round 3
// 2068.329 us; speedup vs baseline: 1.5328x; 1.2111x over previous
//
#include <hip/hip_runtime.h>

// Problem constants (match reference setup_inputs)
#define D 64
constexpr int Pn  = 100000;
constexpr int Un  = 20000;
constexpr int Rn  = 1000;
constexpr int Cn  = 500;
constexpr int Tn  = 50;
constexpr int Bn  = 4096;
constexpr int ETn = 50000;
constexpr int NNZ_COL = 1000000;
constexpr int NNZ_REG = 300000;
constexpr int NNZ_CAT = 300000;
constexpr int NNZ_T   = 1000000;

static inline int cdiv(int a, int b) { return (a + b - 1) / b; }

// ---------------------------------------------------------------------------
// gate: out = x * sigmoid(x @ W + b), two destinations. Grid-capped so the
// 64-VGPR W column amortizes over many grid-strided rows.
// ---------------------------------------------------------------------------
__global__ __launch_bounds__(256) void gate_kernel(
    const float* __restrict__ Xin, const float* __restrict__ W,
    const float* __restrict__ bias, float* __restrict__ Pout,
    float* __restrict__ Aout, int N) {
  __shared__ float sx[4][D];
  int tid = threadIdx.x, wv = tid >> 6, lane = tid & 63;
  float wcol[D];
#pragma unroll
  for (int k = 0; k < D; ++k) wcol[k] = W[k * D + lane];
  float bl = bias[lane];
  for (int row = blockIdx.x * 4 + wv; row < N; row += gridDim.x * 4) {
    float x = Xin[row * D + lane];
    sx[wv][lane] = x;
    float y = 0.f;
#pragma unroll
    for (int k = 0; k < D; ++k) y += sx[wv][k] * wcol[k];
    float s = 1.f / (1.f + __expf(-(y + bl)));
    float o = x * s;
    Pout[row * D + lane] = o;
    Aout[row * D + lane] = o;
  }
}

// Y = X @ W  (N x 64) @ (64 x 64)
__global__ __launch_bounds__(256) void matmul_kernel(
    const float* __restrict__ Xin, const float* __restrict__ W,
    float* __restrict__ Y, int N) {
  __shared__ float sx[4][D];
  int tid = threadIdx.x, wv = tid >> 6, lane = tid & 63;
  float wcol[D];
#pragma unroll
  for (int k = 0; k < D; ++k) wcol[k] = W[k * D + lane];
  for (int row = blockIdx.x * 4 + wv; row < N; row += gridDim.x * 4) {
    sx[wv][lane] = Xin[row * D + lane];
    float y = 0.f;
#pragma unroll
    for (int k = 0; k < D; ++k) y += sx[wv][k] * wcol[k];
    Y[row * D + lane] = y;
  }
}

// Y = A @ W1 + B @ W2  (fused hetero edge update)
__global__ __launch_bounds__(256) void fused2_kernel(
    const float* __restrict__ A, const float* __restrict__ Bm,
    const float* __restrict__ W1, const float* __restrict__ W2,
    float* __restrict__ Y, int N) {
  __shared__ float sa[4][D], sb2[4][D];
  int tid = threadIdx.x, wv = tid >> 6, lane = tid & 63;
  float w1[D], w2[D];
#pragma unroll
  for (int k = 0; k < D; ++k) {
    w1[k] = W1[k * D + lane];
    w2[k] = W2[k * D + lane];
  }
  for (int row = blockIdx.x * 4 + wv; row < N; row += gridDim.x * 4) {
    sa[wv][lane]  = A[row * D + lane];
    sb2[wv][lane] = Bm[row * D + lane];
    float y = 0.f;
#pragma unroll
    for (int k = 0; k < D; ++k) y += sa[wv][k] * w1[k] + sb2[wv][k] * w2[k];
    Y[row * D + lane] = y;
  }
}

// ---------------------------------------------------------------------------
// Dual-direction counting sort -> CSR. Key space is [0,nk1) for dir1 and
// [nk1, nk1+nk2) for dir2; scan of concatenated counts puts dir2 payloads at
// sd[nnz..2nnz). After scatter, cursor[] holds CSR end-pointers.
// ---------------------------------------------------------------------------
__global__ __launch_bounds__(256) void hist2_kernel(
    const int* __restrict__ k1, const int* __restrict__ k2,
    int* __restrict__ counts, int nk1, int nnz) {
  int i = blockIdx.x * blockDim.x + threadIdx.x;
  if (i < nnz) {
    atomicAdd(&counts[k1[i]], 1);
    atomicAdd(&counts[nk1 + k2[i]], 1);
  }
}

// per-block exclusive scan over 4096 elems; block totals out
__global__ __launch_bounds__(1024) void scan_blocks_kernel(
    const int* __restrict__ in, int* __restrict__ out, int* __restrict__ btot,
    int n) {
  __shared__ int lds[16];
  int tid = threadIdx.x, lane = tid & 63, wv = tid >> 6;
  int base = blockIdx.x * 4096;
  int x[4];
  int s = 0;
#pragma unroll
  for (int e = 0; e < 4; ++e) {
    int i = base + tid * 4 + e;
    x[e] = (i < n) ? in[i] : 0;
    s += x[e];
  }
  int sc = s;
#pragma unroll
  for (int d = 1; d < 64; d <<= 1) {
    int y = __shfl_up(sc, d);
    if (lane >= d) sc += y;
  }
  if (lane == 63) lds[wv] = sc;
  __syncthreads();
  if (tid < 16) {
    int w = lds[tid];
#pragma unroll
    for (int d = 1; d < 16; d <<= 1) {
      int y = __shfl_up(w, d);
      if (lane >= d) w += y;
    }
    lds[tid] = w;
  }
  __syncthreads();
  int woff = (wv == 0) ? 0 : lds[wv - 1];
  int excl = woff + sc - s;
#pragma unroll
  for (int e = 0; e < 4; ++e) {
    int i = base + tid * 4 + e;
    if (i < n) out[i] = excl;
    excl += x[e];
  }
  if (tid == 0) btot[blockIdx.x] = lds[15];
}

__global__ __launch_bounds__(64) void scan_totals_kernel(int* btot, int nb) {
  int lane = threadIdx.x;
  int x = (lane < nb) ? btot[lane] : 0;
  int sc = x;
#pragma unroll
  for (int d = 1; d < 64; d <<= 1) {
    int y = __shfl_up(sc, d);
    if (lane >= d) sc += y;
  }
  if (lane < nb) btot[lane] = sc - x;  // exclusive
}

__global__ __launch_bounds__(256) void add_off_kernel(
    int* __restrict__ out, const int* __restrict__ btot, int n) {
  int i = blockIdx.x * blockDim.x + threadIdx.x;
  if (i < n) out[i] += btot[i >> 12];
}

__global__ __launch_bounds__(256) void scatter2_kernel(
    const int* __restrict__ k1, const int* __restrict__ o1,
    const float* __restrict__ v1, const int* __restrict__ k2,
    const int* __restrict__ o2, const float* __restrict__ v2,
    int* __restrict__ cursor, int2* __restrict__ sd, int nk1, int nnz) {
  int i = blockIdx.x * blockDim.x + threadIdx.x;
  if (i >= nnz) return;
  int p1 = atomicAdd(&cursor[k1[i]], 1);
  sd[p1] = make_int2(o1[i], __float_as_int(v1[i]));
  int p2 = atomicAdd(&cursor[nk1 + k2[i]], 1);
  sd[p2] = make_int2(o2[i], __float_as_int(v2[i]));
}

// ---------------------------------------------------------------------------
// CSR SpMM: one wave per destination row; register accumulate; single clean
// 256B row write; no atomics, no pre-memset (empty rows write zeros).
// endp = post-scatter cursor (end pointers); base selects direction segment.
// ---------------------------------------------------------------------------
__global__ __launch_bounds__(256) void spmm_csr_kernel(
    const int* __restrict__ endp, int base, const int2* __restrict__ sd,
    const float* __restrict__ X, float* __restrict__ Y, int nrows) {
  int lane = threadIdx.x & 63;
  int w = (int)((blockIdx.x * (long)blockDim.x + threadIdx.x) >> 6);
  if (w >= nrows) return;
  int idx = base + w;
  int start = (idx == 0) ? 0 : endp[idx - 1];
  int end = endp[idx];
  float a0 = 0.f, a1 = 0.f, a2 = 0.f, a3 = 0.f;
  int n = start;
  for (; n + 4 <= end; n += 4) {
    int2 c0 = sd[n], c1 = sd[n + 1], c2 = sd[n + 2], c3 = sd[n + 3];
    a0 += __int_as_float(c0.y) * X[(size_t)c0.x * D + lane];
    a1 += __int_as_float(c1.y) * X[(size_t)c1.x * D + lane];
    a2 += __int_as_float(c2.y) * X[(size_t)c2.x * D + lane];
    a3 += __int_as_float(c3.y) * X[(size_t)c3.x * D + lane];
  }
  for (; n < end; ++n) {
    int2 cv = sd[n];
    a0 += __int_as_float(cv.y) * X[(size_t)cv.x * D + lane];
  }
  Y[(size_t)w * D + lane] = (a0 + a1) + (a2 + a3);
}

// p += t; acc += p   (float4)
__global__ __launch_bounds__(256) void resid2_kernel(
    float4* __restrict__ p, const float4* __restrict__ t,
    float4* __restrict__ acc, int n4) {
  int i = blockIdx.x * blockDim.x + threadIdx.x;
  if (i < n4) {
    float4 a = p[i], b = t[i], c = acc[i];
    a.x += b.x; a.y += b.y; a.z += b.z; a.w += b.w;
    p[i] = a;
    c.x += a.x; c.y += a.y; c.z += a.z; c.w += a.w;
    acc[i] = c;
  }
}

// a = src; b = src  (float4)
__global__ __launch_bounds__(256) void copy2_kernel(
    const float4* __restrict__ s, float4* __restrict__ a,
    float4* __restrict__ b, int n4) {
  int i = blockIdx.x * blockDim.x + threadIdx.x;
  if (i < n4) {
    float4 v = s[i];
    a[i] = v;
    b[i] = v;
  }
}

// Final pooling: masked mean over T of 4 padded tables + user add, scale 1/3.
__global__ __launch_bounds__(256) void final_kernel(
    const int* __restrict__ user_idx, const int* __restrict__ seq,
    const int* __restrict__ mask, const float* __restrict__ colP,
    const float* __restrict__ transP, const float* __restrict__ regP,
    const float* __restrict__ catP, const float* __restrict__ colU,
    float* __restrict__ out) {
  int wid = (int)((blockIdx.x * blockDim.x + threadIdx.x) >> 6);
  int lane = threadIdx.x & 63;
  if (wid >= Bn) return;
  float sc = 0.f, st = 0.f, sr = 0.f, sca = 0.f;
  int cnt = 0;
  for (int t = 0; t < Tn; ++t) {
    int m = mask[wid * Tn + t];
    int idx = seq[wid * Tn + t];
    cnt += m;
    if (m && idx < Pn) {
      sc  += colP[idx * D + lane];
      st  += transP[idx * D + lane];
      sr  += regP[idx * D + lane];
      sca += catP[idx * D + lane];
    }
  }
  float dn = 1.f / (float)(cnt > 0 ? cnt : 1);
  const float inv = 1.f / 3.f;  // 1/(N_LAYERS+1), common to all four nets
  int u = user_idx[wid];
  out[0 * Bn * D + wid * D + lane] = (colU[u * D + lane] + sc * dn) * inv;
  out[1 * Bn * D + wid * D + lane] = st * dn * inv;
  out[2 * Bn * D + wid * D + lane] = sr * dn * inv;
  out[3 * Bn * D + wid * D + lane] = sca * dn * inv;
}

extern "C" void kernel_launch(void* const* d_in, const int* in_sizes, int n_in,
                              void* d_out, int out_size, void* d_ws,
                              size_t ws_size, hipStream_t stream) {
  (void)in_sizes; (void)n_in; (void)out_size; (void)ws_size;
  const int*   user_idx      = (const int*)d_in[0];
  const int*   user_seq      = (const int*)d_in[1];
  const int*   user_seq_mask = (const int*)d_in[2];
  const int*   col_poi_idx   = (const int*)d_in[3];
  const int*   col_user_idx  = (const int*)d_in[4];
  const float* col_vals_pe   = (const float*)d_in[5];
  const float* col_vals_ep   = (const float*)d_in[6];
  const int*   reg_poi_idx   = (const int*)d_in[7];
  const int*   reg_region_idx= (const int*)d_in[8];
  const float* reg_vals_pe   = (const float*)d_in[9];
  const float* reg_vals_ep   = (const float*)d_in[10];
  const int*   cat_poi_idx   = (const int*)d_in[11];
  const int*   cat_cat_idx   = (const int*)d_in[12];
  const float* cat_vals_pe   = (const float*)d_in[13];
  const float* cat_vals_ep   = (const float*)d_in[14];
  const int*   trans_poi_idx = (const int*)d_in[15];
  const int*   trans_edge_idx= (const int*)d_in[16];
  const float* trans_vals_tar= (const float*)d_in[17];
  const float* trans_vals_src= (const float*)d_in[18];
  const float* poi_emb       = (const float*)d_in[19];
  const float* user_emb      = (const float*)d_in[20];
  const float* region_emb    = (const float*)d_in[21];
  const float* cat_emb       = (const float*)d_in[22];
  const float* w_gate_col    = (const float*)d_in[23];
  const float* b_gate_col    = (const float*)d_in[24];
  const float* w_gate_trans  = (const float*)d_in[25];
  const float* b_gate_trans  = (const float*)d_in[26];
  const float* w_gate_reg    = (const float*)d_in[27];
  const float* b_gate_reg    = (const float*)d_in[28];
  const float* w_gate_cat    = (const float*)d_in[29];
  const float* b_gate_cat    = (const float*)d_in[30];
  const float* col_Wp = (const float*)d_in[31];
  const float* col_We = (const float*)d_in[32];
  const float* col_Wf = (const float*)d_in[33];
  const float* reg_Wp = (const float*)d_in[34];
  const float* reg_We = (const float*)d_in[35];
  const float* reg_Wf = (const float*)d_in[36];
  const float* cat_Wp = (const float*)d_in[37];
  const float* cat_We = (const float*)d_in[38];
  const float* cat_Wf = (const float*)d_in[39];

  float* ws = (float*)d_ws;
  size_t off = 0;
  auto alloc = [&](size_t n) { float* p = ws + off; off += n; return p; };
  const size_t PD = (size_t)Pn * D;   // 6.4M floats
  const size_t UD = (size_t)Un * D;   // 1.28M
  const size_t ED = (size_t)ETn * D;  // 3.2M

  float* colP   = alloc(PD);
  float* regP   = alloc(PD);
  float* catP   = alloc(PD);
  float* transP = alloc(PD);
  float* colU   = alloc(UD);
  float* p_buf  = alloc(PD);
  float* tmpP   = alloc(PD);
  float* e_buf  = alloc(UD);          // hetero edge features (max Un rows)
  float* tmpE2  = alloc(UD);
  float* tmpE1  = alloc(ED);          // pe-spmm dest (max ETn rows)
  float* acce   = alloc((size_t)Rn * D);  // scratch acc_e for reg/cat
  float* WeWf   = alloc(D * D);
  int2*  sd     = (int2*)alloc(4 * (size_t)NNZ_T);  // both dirs, 2*nnz int2
  int*   counts = (int*)alloc(160000);
  int*   cursor = (int*)alloc(160000);
  int*   btot   = (int*)alloc(64);

  const int GCAP = 1024;  // grid cap for dense wave-per-row kernels

  // Build CSR for both directions of a graph in one pipeline.
  auto sort2 = [&](const int* k1, const int* o1, const float* v1,
                   const int* k2, const int* o2, const float* v2, int nk1,
                   int nk2, int nnz) {
    int nk = nk1 + nk2;
    hipMemsetAsync(counts, 0, (size_t)nk * sizeof(int), stream);
    hist2_kernel<<<cdiv(nnz, 256), 256, 0, stream>>>(k1, k2, counts, nk1, nnz);
    int nb = cdiv(nk, 4096);
    scan_blocks_kernel<<<nb, 1024, 0, stream>>>(counts, cursor, btot, nk);
    scan_totals_kernel<<<1, 64, 0, stream>>>(btot, nb);
    add_off_kernel<<<cdiv(nk, 256), 256, 0, stream>>>(cursor, btot, nk);
    scatter2_kernel<<<cdiv(nnz, 256), 256, 0, stream>>>(k1, o1, v1, k2, o2, v2,
                                                        cursor, sd, nk1, nnz);
  };

  auto spmm = [&](int base, const float* X, float* Y, int nrows) {
    spmm_csr_kernel<<<cdiv(nrows, 4), 256, 0, stream>>>(cursor, base, sd, X, Y,
                                                        nrows);
  };

  auto hetero = [&](const float* wg, const float* bg, const float* edge_emb,
                    int Ne, const int* poi_idx, const int* edge_idx,
                    const float* v_pe, const float* v_ep, const float* Wp,
                    const float* We, const float* Wf, int nnz, float* accP,
                    float* accE) {
    // dir1: dest=edge keys, payload (poi, v_pe); dir2: dest=poi, (edge, v_ep)
    sort2(edge_idx, poi_idx, v_pe, poi_idx, edge_idx, v_ep, Ne, Pn, nnz);
    gate_kernel<<<GCAP, 256, 0, stream>>>(poi_emb, wg, bg, p_buf, accP, Pn);
    copy2_kernel<<<cdiv(Ne * D / 4, 256), 256, 0, stream>>>(
        (const float4*)edge_emb, (float4*)e_buf, (float4*)accE, Ne * D / 4);
    matmul_kernel<<<16, 256, 0, stream>>>(We, Wf + D * D, WeWf, D);  // We@Wf_bot
    for (int l = 0; l < 2; ++l) {
      matmul_kernel<<<GCAP, 256, 0, stream>>>(p_buf, Wp, tmpP, Pn);
      spmm(0, tmpP, tmpE1, Ne);                   // poi_msg (dest=edge rows)
      fused2_kernel<<<min(cdiv(Ne, 4), GCAP), 256, 0, stream>>>(
          tmpE1, e_buf, Wf, WeWf, tmpE2, Ne);
      spmm(Ne, tmpE2, tmpP, Pn);                  // prop (dest=poi rows)
      resid2_kernel<<<cdiv((int)(PD / 4), 256), 256, 0, stream>>>(
          (float4*)p_buf, (const float4*)tmpP, (float4*)accP, (int)(PD / 4));
      resid2_kernel<<<cdiv(Ne * D / 4, 256), 256, 0, stream>>>(
          (float4*)e_buf, (const float4*)tmpE2, (float4*)accE, Ne * D / 4);
    }
  };

  // --- three hetero nets (acc scaled by 1/3 in final kernel) ---
  hetero(w_gate_col, b_gate_col, user_emb, Un, col_poi_idx, col_user_idx,
         col_vals_pe, col_vals_ep, col_Wp, col_We, col_Wf, NNZ_COL, colP, colU);
  hetero(w_gate_reg, b_gate_reg, region_emb, Rn, reg_poi_idx, reg_region_idx,
         reg_vals_pe, reg_vals_ep, reg_Wp, reg_We, reg_Wf, NNZ_REG, regP, acce);
  hetero(w_gate_cat, b_gate_cat, cat_emb, Cn, cat_poi_idx, cat_cat_idx,
         cat_vals_pe, cat_vals_ep, cat_Wp, cat_We, cat_Wf, NNZ_CAT, catP, acce);

  // --- directed trans net ---
  sort2(trans_edge_idx, trans_poi_idx, trans_vals_tar, trans_poi_idx,
        trans_edge_idx, trans_vals_src, ETn, Pn, NNZ_T);
  gate_kernel<<<GCAP, 256, 0, stream>>>(poi_emb, w_gate_trans, b_gate_trans,
                                        p_buf, transP, Pn);
  for (int l = 0; l < 2; ++l) {
    spmm(0, p_buf, tmpE1, ETn);    // msg_tar (dest=edge rows)
    spmm(ETn, tmpE1, tmpP, Pn);    // msg_src (dest=poi rows)
    resid2_kernel<<<cdiv((int)(PD / 4), 256), 256, 0, stream>>>(
        (float4*)p_buf, (const float4*)tmpP, (float4*)transP, (int)(PD / 4));
  }

  // --- sequence pooling + output ---
  final_kernel<<<cdiv(Bn * 64, 256), 256, 0, stream>>>(
      user_idx, user_seq, user_seq_mask, colP, transP, regP, catP, colU,
      (float*)d_out);
}